// Round 6
// baseline (97.170 us; speedup 1.0000x reference)
//
#include <hip/hip_runtime.h>

typedef unsigned int uint;
typedef unsigned short ushort;
typedef unsigned long long ull;
typedef __attribute__((ext_vector_type(8))) short short8;    // 8 bf16 MFMA A/B frag
typedef __attribute__((ext_vector_type(4))) float f32x4;
typedef __attribute__((ext_vector_type(16))) float f32x16;   // 32x32 MFMA C/D
typedef __attribute__((ext_vector_type(4))) uint uint4v;
typedef __attribute__((ext_vector_type(2))) uint uint2v;

#define BATCH 4
#define CH 64
#define NPIX 4096
#define LOG2E 1.44269504f

// ws layout (ushort elems). K/V are COMPACTED per 256-pixel region: valid keys
// first (slot term 0), invalid keys in the tail (slot term -1e30). Q stays at
// original pixel positions (invalid query rows zeroed).
// qf[b][qt:128][h:2][m':32][jj:8]
// kf[b][jt:128][h:2][j':32][jj:8]
// vtf[b][jt:128][ct:2][h:2][hp:2][c':32][jj:8]
// nv[b][region:16]   (ushort)  valid-key count per 256-key region
// qm[b][n:4096]      (ushort)  query validity
// Vpart[b][c:64][chunk:16] (f32) per-256-pixel-chunk sums of V (all pixels)
#define WSQ 0
#define WSK 262144
#define WSV 524288
#define WSNV 1572864
#define WSQM 1572928
#define WSVPU 1589312          // float region at byte 3178624 (16 KB)

__device__ __forceinline__ ushort f2bf(float f) {            // RNE f32->bf16 (scalar)
    union { float f; uint u; } a; a.f = f;
    const uint u = a.u;
    return (ushort)((u + 0x7FFFu + ((u >> 16) & 1u)) >> 16);
}
// single-instruction packed f32->bf16 (RNE): dst.lo = bf16(a), dst.hi = bf16(b)
__device__ __forceinline__ uint cvtpk(float a, float b) {
    uint r;
    asm("v_cvt_pk_bf16_f32 %0, %1, %2" : "=v"(r) : "v"(a), "v"(b));
    return r;
}

// ---------------- MFMA projections -> frag-major bf16 q,k,v (compacted K/V) ----
// Packed GEMM: 96 rows [q(8)*LOG2E; k(8); v(64); pad(16)] x K=64 x 16384 px.
// grid (128): block = half of a 256-px compaction region; 4 waves x 1 px-tile(32).
// Split-bf16 keeps precision: x = xhi+xlo (all tiles); W = Whi+Wlo for q/k tile.
// Both half-blocks redundantly compute the region ballot (deterministic slots).
__global__ __launch_bounds__(256) void proj_kernel(
    const float* __restrict__ x, const int* __restrict__ mask,
    const float* __restrict__ Wq, const float* __restrict__ bq,
    const float* __restrict__ Wk, const float* __restrict__ bk,
    const float* __restrict__ Wv, const float* __restrict__ bv,
    ushort* __restrict__ ws)
{
    __shared__ ushort WL[6144];      // hi: [rt3][s4][h2][row32][jj8] bf16
    __shared__ ushort WLlo[2048];    // lo residual, rt0 only (q/k rows + v0-15)
    __shared__ float  biasL[96];
    __shared__ ushort slotS[256];
    __shared__ ushort qmS2[256];
    __shared__ int    wcnt[4];
    __shared__ float  sxL[64];

    const int tid  = threadIdx.x;
    const int wid  = tid >> 6, lane = tid & 63;
    const int hl   = lane >> 5, col = lane & 31;
    const int blk  = blockIdx.x;          // 0..127
    const int reg  = blk >> 1;            // 0..63 region
    const int half = blk & 1;
    const int b    = reg >> 4, rr = reg & 15;
    const int pixg = reg * 256 + tid;     // global pixel of this thread's ballot slot

    // ---- stage W (bf16 frag-major; LOG2E folded into q rows; lo residual rt0) ----
    for (int i = tid; i < 6144; i += 256) {
        const int rt = i >> 11, rem = i & 2047;
        const int s = rem >> 9, rem2 = rem & 511;
        const int h2 = rem2 >> 8, row = (rem2 & 255) >> 3, jj = rem2 & 7;
        const int R = rt * 32 + row, c = s * 16 + h2 * 8 + jj;
        float v = 0.f;
        if (R < 8)       v = Wq[R * 64 + c] * LOG2E;
        else if (R < 16) v = Wk[(R - 8) * 64 + c];
        else if (R < 80) v = Wv[(R - 16) * 64 + c];
        const ushort hi = f2bf(v);
        WL[i] = hi;
        if (rt == 0) {
            const float lo = v - __uint_as_float((uint)hi << 16);
            WLlo[i] = f2bf(lo);
        }
    }
    if (tid < 96)
        biasL[tid] = (tid < 8) ? bq[tid] * LOG2E
                   : (tid < 16) ? bk[tid - 8]
                   : (tid < 80) ? bv[tid - 16] : 0.f;

    // ---- compaction ballot (identical in both half-blocks; R3 logic) ----
    const int qm = mask[pixg];
    const ull bal = __ballot(qm != 0);
    if (lane == 0) wcnt[wid] = __popcll(bal);
    __syncthreads();
    int offV = 0, offI = 0, nvb = 0;
#pragma unroll
    for (int w = 0; w < 4; w++) {
        const int cw = wcnt[w];
        if (w < wid) { offV += cw; offI += 64 - cw; }
        nvb += cw;
    }
    const int rankV = __popcll(bal & ((1ull << lane) - 1ull));
    const int slot = qm ? (offV + rankV) : (nvb + offI + (lane - rankV));
    slotS[tid] = (ushort)slot;
    qmS2[tid] = (ushort)qm;
    if (half == 0) {
        ws[WSQM + pixg] = (ushort)qm;
        if (tid == 0) ws[WSNV + b * 16 + rr] = (ushort)nvb;
    }
    __syncthreads();   // covers WL/WLlo/biasL/slotS/qmS2

    // ---- main: one 32-px tile per wave ----
    const int p = half * 4 + wid;                 // px-tile 0..7 of region
    const int n0 = p * 32;
    const float* xb = x + (size_t)b * (CH * NPIX) + rr * 256 + n0 + col;

    // x loads (32 per lane, all independent)
    float xr[4][8];
#pragma unroll
    for (int s = 0; s < 4; s++)
#pragma unroll
        for (int jj = 0; jj < 8; jj++)
            xr[s][jj] = xb[(size_t)(s * 16 + hl * 8 + jj) * NPIX];

    // B-frags: hi = RNE bf16; lo = exact residual, re-rounded
    uint Bh[4][4], Bl[4][4];
#pragma unroll
    for (int s = 0; s < 4; s++)
#pragma unroll
        for (int w2 = 0; w2 < 4; w2++) {
            const float a = xr[s][2 * w2], b2 = xr[s][2 * w2 + 1];
            const uint u = cvtpk(a, b2);
            Bh[s][w2] = u;
            const float ha = __uint_as_float(u << 16);
            const float hb = __uint_as_float(u & 0xFFFF0000u);
            Bl[s][w2] = cvtpk(a - ha, b2 - hb);
        }

    // acc init = bias (C/D crow mapping, verified)
    f32x16 a0, a1, a2;
#pragma unroll
    for (int r = 0; r < 16; r++) {
        const int crow = (r & 3) + 8 * (r >> 2) + 4 * hl;
        a0[r] = biasL[crow]; a1[r] = biasL[32 + crow]; a2[r] = biasL[64 + crow];
    }

#pragma unroll
    for (int s = 0; s < 4; s++) {
        const short8 A0  = *(const short8*)&WL[((0 * 4 + s) * 2 + hl) * 256 + col * 8];
        const short8 A0l = *(const short8*)&WLlo[(s * 2 + hl) * 256 + col * 8];
        const short8 A1  = *(const short8*)&WL[((1 * 4 + s) * 2 + hl) * 256 + col * 8];
        const short8 A2  = *(const short8*)&WL[((2 * 4 + s) * 2 + hl) * 256 + col * 8];
        const short8 bh = *(const short8*)&Bh[s], bl = *(const short8*)&Bl[s];
        a0 = __builtin_amdgcn_mfma_f32_32x32x16_bf16(A0, bh, a0, 0, 0, 0);
        a0 = __builtin_amdgcn_mfma_f32_32x32x16_bf16(A0, bl, a0, 0, 0, 0);
        a0 = __builtin_amdgcn_mfma_f32_32x32x16_bf16(A0l, bh, a0, 0, 0, 0);
        a1 = __builtin_amdgcn_mfma_f32_32x32x16_bf16(A1, bh, a1, 0, 0, 0);
        a1 = __builtin_amdgcn_mfma_f32_32x32x16_bf16(A1, bl, a1, 0, 0, 0);
        a2 = __builtin_amdgcn_mfma_f32_32x32x16_bf16(A2, bh, a2, 0, 0, 0);
        a2 = __builtin_amdgcn_mfma_f32_32x32x16_bf16(A2, bl, a2, 0, 0, 0);
    }

    // ---- stores (lane col = px; rows via crow) ----
    const int rpx = n0 + col;
    const int qv = qmS2[rpx];
    const int slt = slotS[rpx];
    const int js = rr * 8 + (slt >> 5), jl = slt & 31;

    { // q: regs 0-3 of a0 -> d = r + 4*hl, ORIGINAL position
        const float sc = qv ? 1.f : 0.f;
        uint2v qw; qw.x = cvtpk(a0[0] * sc, a0[1] * sc); qw.y = cvtpk(a0[2] * sc, a0[3] * sc);
        ushort* qfp = ws + WSQ + (size_t)b * 65536 + (size_t)(rr * 8 + p) * 512;
        *(uint2v*)(qfp + col * 8 + 4 * hl) = qw;
        if (hl == 0) {
            uint4v h4; h4.x = qv ? 0x3F80u : 0u; h4.y = 0u; h4.z = 0u; h4.w = 0u;
            *(uint4v*)(qfp + 256 + col * 8) = h4;
        }
    }
    { // k: regs 4-7 of a0 -> d = (r&3) + 4*hl, COMPACTED position
        uint2v kw; kw.x = cvtpk(a0[4], a0[5]); kw.y = cvtpk(a0[6], a0[7]);
        ushort* kfp = ws + WSK + (size_t)b * 65536 + (size_t)js * 512;
        *(uint2v*)(kfp + jl * 8 + 4 * hl) = kw;
        if (hl == 0) {
            uint4v h4; h4.x = (uint)f2bf(qv ? 0.f : -1e30f); h4.y = 0u; h4.z = 0u; h4.w = 0u;
            *(uint4v*)(kfp + 256 + jl * 8) = h4;
        }
    }
    { // v: c = CB + (r&3) + 4*hl; addr = js*2048 + (c>>5)*1024 + h*512 + hp*256 + (c&31)*8 + jj
        ushort* vp = ws + WSV + (size_t)b * 262144 + (size_t)js * 2048
                   + (jl >> 4) * 512 + ((jl >> 3) & 1) * 256 + (jl & 7) + hl * 32;
#define VQUAD(ACC, RB, CB) do {                                                      \
        ushort* q_ = vp + ((CB) >> 5) * 1024 + ((CB) & 31) * 8;                      \
        const uint u0 = cvtpk((ACC)[(RB)], (ACC)[(RB) + 1]);                         \
        const uint u1 = cvtpk((ACC)[(RB) + 2], (ACC)[(RB) + 3]);                     \
        q_[0]  = (ushort)u0; q_[8]  = (ushort)(u0 >> 16);                            \
        q_[16] = (ushort)u1; q_[24] = (ushort)(u1 >> 16);                            \
} while (0)
        VQUAD(a0, 8, 0);  VQUAD(a0, 12, 8);
        VQUAD(a1, 0, 16); VQUAD(a1, 4, 24); VQUAD(a1, 8, 32); VQUAD(a1, 12, 40);
        VQUAD(a2, 0, 48); VQUAD(a2, 4, 56);
#undef VQUAD
    }

    // ---- Vpart = Wv . (sum_px x) + 256*bv  (== R3's per-region f32 V sums) ----
    __syncthreads();
    if (half == 0 && tid < 64) {
        const float* xrow = x + ((size_t)b * CH + tid) * NPIX + rr * 256;
        float s = 0.f;
#pragma unroll
        for (int i2 = 0; i2 < 64; i2++) {
            const float4 v4 = *(const float4*)&xrow[i2 * 4];
            s += ((v4.x + v4.y) + (v4.z + v4.w));
        }
        sxL[tid] = s;
    }
    __syncthreads();
    if (half == 0 && tid < 64) {
        const float* wr = Wv + tid * 64;
        float t = 256.f * bv[tid];
#pragma unroll
        for (int c4 = 0; c4 < 16; c4++) {
            const float4 w4 = *(const float4*)&wr[c4 * 4];
            t += w4.x * sxL[c4 * 4] + w4.y * sxL[c4 * 4 + 1]
               + w4.z * sxL[c4 * 4 + 2] + w4.w * sxL[c4 * 4 + 3];
        }
        ((float*)(ws + WSVPU))[(b * 64 + tid) * 16 + rr] = t;
    }
}

// ---------------- LDS-free MFMA flash attention over COMPACTED keys ----------------
// grid (64, 4): 64-query tile, 512 thr = 8 waves. Active 32-key chunks
// (lc*32 < nv[region]) are flattened into a list and round-robined over waves:
// ~44% of iterations (exp2/MFMA/pack/loads) are skipped vs the dense loop.
__global__ __launch_bounds__(512, 2) void attn_kernel(
    const ushort* __restrict__ ws, const float* __restrict__ x,
    const float* __restrict__ gamma, float* __restrict__ out)
{
    __shared__ float Obuf[8][32][36];     // 36.9 KB
    __shared__ float Lb[2][8][32];
    __shared__ float Linv[2][32];
    __shared__ float VmeanS[64];
    __shared__ ushort qmS[64];
    __shared__ ushort nvS[16];
    __shared__ ushort jtT[8][17];         // per-wave active-chunk list (+pad entry)

    const int tid  = threadIdx.x;
    const int wid  = tid >> 6;
    const int lane = tid & 63;
    const int hl   = lane >> 5;
    const int col  = lane & 31;
    const int b    = blockIdx.y;
    const int bx   = blockIdx.x;          // queries bx*64 .. bx*64+63

    const ushort* qf = ws + WSQ + (size_t)b * 65536 + (size_t)(2 * bx) * 512;
    const ushort* kf = ws + WSK + (size_t)b * 65536;
    const ushort* vt = ws + WSV + (size_t)b * 262144;

    const short8 qfA = *(const short8*)(qf + lane * 8);
    const short8 qfB = *(const short8*)(qf + 512 + lane * 8);

    // stage nv / qmask / Vmean
    if (tid < 16) nvS[tid] = ws[WSNV + b * 16 + tid];
    if (tid >= 64 && tid < 128) qmS[tid - 64] = ws[WSQM + b * 4096 + bx * 64 + (tid - 64)];
    if (tid >= 128 && tid < 192) {
        const int c = tid - 128;
        const float* vpf = (const float*)(ws + WSVPU);
        float s = 0.f;
#pragma unroll
        for (int k2 = 0; k2 < 16; k2++) s += vpf[(b * 64 + c) * 16 + k2];
        VmeanS[c] = s * (1.0f / 4096.0f);
    }
    __syncthreads();

    int A = 0;
#pragma unroll
    for (int r2 = 0; r2 < 16; r2++) {
        int a = ((int)nvS[r2] + 31) >> 5; if (a > 8) a = 8;
        A += a;
    }
    if (tid < 128) {                       // flatten active chunks -> (region, lc)
        const int w = tid >> 4, ii = tid & 15, ci = w + ii * 8;
        int Acc = 0, ent = 0;
#pragma unroll
        for (int r2 = 0; r2 < 16; r2++) {
            int a = ((int)nvS[r2] + 31) >> 5; if (a > 8) a = 8;
            if (ci >= Acc && ci < Acc + a) ent = r2 * 8 + (ci - Acc);
            Acc += a;
        }
        jtT[w][ii] = (ushort)ent;
    }
    if (tid < 8) jtT[tid][16] = 0;
    __syncthreads();

    const int niter = (A - wid + 7) >> 3;  // A >= 16 always

    f32x16 accA0, accA1, accB0, accB1, zf;
#pragma unroll
    for (int r = 0; r < 16; r++) { accA0[r] = 0.f; accA1[r] = 0.f; accB0[r] = 0.f; accB1[r] = 0.f; zf[r] = 0.f; }
    float lsA = 0.f, lsB = 0.f;

    // prefetch first active chunk
    int jc = jtT[wid][0];
    uint4v kn   = *(const uint4v*)(kf + (size_t)jc * 512 + lane * 8);
    uint4v vn00 = *(const uint4v*)(vt + (size_t)((jc * 2 + 0) * 2 + 0) * 512 + lane * 8);
    uint4v vn01 = *(const uint4v*)(vt + (size_t)((jc * 2 + 0) * 2 + 1) * 512 + lane * 8);
    uint4v vn10 = *(const uint4v*)(vt + (size_t)((jc * 2 + 1) * 2 + 0) * 512 + lane * 8);
    uint4v vn11 = *(const uint4v*)(vt + (size_t)((jc * 2 + 1) * 2 + 1) * 512 + lane * 8);

// exp2 -> tree lsum -> cvt_pk bf16 -> permlane32_swap B-frags -> 4 PV MFMAs
#define QK_PV(SFRAG, LSUM, A0, A1) do {                                                              \
    float p[16];                                                                                     \
    _Pragma("unroll") for (int r = 0; r < 16; r++) p[r] = __builtin_amdgcn_exp2f((SFRAG)[r]);        \
    LSUM += (((p[0] + p[1]) + (p[2] + p[3])) + ((p[4] + p[5]) + (p[6] + p[7])))                      \
          + (((p[8] + p[9]) + (p[10] + p[11])) + ((p[12] + p[13]) + (p[14] + p[15])));               \
    uint P[8];                                                                                       \
    _Pragma("unroll") for (int r = 0; r < 8; r++) P[r] = cvtpk(p[2 * r], p[2 * r + 1]);              \
    const uint2v s02 = __builtin_amdgcn_permlane32_swap(P[0], P[2], false, false);                   \
    const uint2v s13 = __builtin_amdgcn_permlane32_swap(P[1], P[3], false, false);                   \
    const uint2v s46 = __builtin_amdgcn_permlane32_swap(P[4], P[6], false, false);                   \
    const uint2v s57 = __builtin_amdgcn_permlane32_swap(P[5], P[7], false, false);                   \
    uint4v B0, B1;                                                                                   \
    B0.x = s02.x; B0.y = s13.x; B0.z = s02.y; B0.w = s13.y;                                          \
    B1.x = s46.x; B1.y = s57.x; B1.z = s46.y; B1.w = s57.y;                                          \
    __builtin_amdgcn_s_setprio(1);                                                                   \
    A0 = __builtin_amdgcn_mfma_f32_32x32x16_bf16(*(const short8*)&c00, *(const short8*)&B0, A0, 0, 0, 0); \
    A0 = __builtin_amdgcn_mfma_f32_32x32x16_bf16(*(const short8*)&c01, *(const short8*)&B1, A0, 0, 0, 0); \
    A1 = __builtin_amdgcn_mfma_f32_32x32x16_bf16(*(const short8*)&c10, *(const short8*)&B0, A1, 0, 0, 0); \
    A1 = __builtin_amdgcn_mfma_f32_32x32x16_bf16(*(const short8*)&c11, *(const short8*)&B1, A1, 0, 0, 0); \
    __builtin_amdgcn_s_setprio(0);                                                                   \
} while (0)

    for (int i = 0; i < niter; i++) {
        const int jn = jtT[wid][i + 1];
        const uint4v kc = kn, c00 = vn00, c01 = vn01, c10 = vn10, c11 = vn11;
        if (i + 1 < niter) {                 // prefetch next active chunk
            kn   = *(const uint4v*)(kf + (size_t)jn * 512 + lane * 8);
            vn00 = *(const uint4v*)(vt + (size_t)((jn * 2 + 0) * 2 + 0) * 512 + lane * 8);
            vn01 = *(const uint4v*)(vt + (size_t)((jn * 2 + 0) * 2 + 1) * 512 + lane * 8);
            vn10 = *(const uint4v*)(vt + (size_t)((jn * 2 + 1) * 2 + 0) * 512 + lane * 8);
            vn11 = *(const uint4v*)(vt + (size_t)((jn * 2 + 1) * 2 + 1) * 512 + lane * 8);
        }

        const f32x16 sA = __builtin_amdgcn_mfma_f32_32x32x16_bf16(*(const short8*)&kc, qfA, zf, 0, 0, 0);
        const f32x16 sB = __builtin_amdgcn_mfma_f32_32x32x16_bf16(*(const short8*)&kc, qfB, zf, 0, 0, 0);

        QK_PV(sA, lsA, accA0, accA1);
        QK_PV(sB, lsB, accB0, accB1);
    }
#undef QK_PV

    // ---- 8-way wave merge (waves held disjoint key chunks) ----
    const float lwA = lsA + __shfl_xor(lsA, 32);
    const float lwB = lsB + __shfl_xor(lsB, 32);
    if (hl == 0) { Lb[0][wid][col] = lwA; Lb[1][wid][col] = lwB; }
    __syncthreads();
    if (tid < 64) {
        const int q = tid >> 5, m = tid & 31;
        float s = 0.f;
#pragma unroll
        for (int w = 0; w < 8; w++) s += Lb[q][w][m];
        Linv[q][m] = 1.f / s;
    }

    const float gm = gamma[0];

// stage 8 waves' partial O^T, 8-way reduce, fused epilogue with invalid-query override
#define MERGE_PASS(ACC, QSEL, CHALF) do {                                                            \
    __syncthreads();                                                                                 \
    _Pragma("unroll") for (int r = 0; r < 16; r++) {                                                 \
        const int crow = (r & 3) + 8 * (r >> 2) + 4 * hl;    /* verified 32x32 C/D mapping */        \
        Obuf[wid][crow][col] = (ACC)[r];                                                             \
    }                                                                                                \
    __syncthreads();                                                                                 \
    {                                                                                                \
        const int c = tid >> 4, m0 = (tid & 15) * 2;                                                 \
        float o0 = 0.f, o1 = 0.f;                                                                    \
        _Pragma("unroll") for (int w = 0; w < 8; w++) { o0 += Obuf[w][c][m0]; o1 += Obuf[w][c][m0 + 1]; } \
        const int cg = (CHALF) * 32 + c;                                                             \
        const int mi = (QSEL) * 32 + m0;                                                             \
        const size_t base = (((size_t)(b * CH + cg)) << 12) + bx * 64 + (QSEL) * 32 + m0;            \
        const float2 xv = *(const float2*)&x[base];                                                  \
        float2 rv;                                                                                   \
        rv.x = (qmS[mi]     ? gm * o0 * Linv[QSEL][m0]     : gm * VmeanS[cg]) + xv.x;                \
        rv.y = (qmS[mi + 1] ? gm * o1 * Linv[QSEL][m0 + 1] : gm * VmeanS[cg]) + xv.y;                \
        *(float2*)&out[base] = rv;                                                                   \
    }                                                                                                \
} while (0)

    MERGE_PASS(accA0, 0, 0);
    MERGE_PASS(accA1, 0, 1);
    MERGE_PASS(accB0, 1, 0);
    MERGE_PASS(accB1, 1, 1);
#undef MERGE_PASS
}

extern "C" void kernel_launch(void* const* d_in, const int* in_sizes, int n_in,
                              void* d_out, int out_size, void* d_ws, size_t ws_size,
                              hipStream_t stream) {
    const float* x     = (const float*)d_in[0];
    const int*   mask  = (const int*)d_in[1];
    const float* Wq    = (const float*)d_in[2];
    const float* bq    = (const float*)d_in[3];
    const float* Wk    = (const float*)d_in[4];
    const float* bk    = (const float*)d_in[5];
    const float* Wv    = (const float*)d_in[6];
    const float* bv    = (const float*)d_in[7];
    const float* gamma = (const float*)d_in[8];
    float* out  = (float*)d_out;
    ushort* ws  = (ushort*)d_ws;     // ~3.2 MB used

    proj_kernel<<<dim3(128), 256, 0, stream>>>(x, mask, Wq, bq, Wk, bk, Wv, bv, ws);
    attn_kernel<<<dim3(64, 4), 512, 0, stream>>>(ws, x, gamma, out);
}

// Round 7
// 95.638 us; speedup vs baseline: 1.0160x; 1.0160x over previous
//
#include <hip/hip_runtime.h>

typedef unsigned int uint;
typedef unsigned short ushort;
typedef unsigned long long ull;
typedef __attribute__((ext_vector_type(8))) short short8;    // 8 bf16 MFMA A/B frag
typedef __attribute__((ext_vector_type(4))) float f32x4;
typedef __attribute__((ext_vector_type(16))) float f32x16;   // 32x32 MFMA C/D
typedef __attribute__((ext_vector_type(4))) uint uint4v;
typedef __attribute__((ext_vector_type(2))) uint uint2v;

#define BATCH 4
#define CH 64
#define NPIX 4096
#define LOG2E 1.44269504f

// ws layout (ushort elems). K/V are COMPACTED per 256-pixel region: valid keys
// first (slot term 0), invalid keys in the tail (slot term -1e30). Q stays at
// original pixel positions (invalid query rows zeroed).
// qf[b][qt:128][h:2][m':32][jj:8]
// kf[b][jt:128][h:2][j':32][jj:8]
// vtf[b][jt:128][ct:2][h:2][hp:2][c':32][jj:8]
// nv[b][region:16]   (ushort)  valid-key count per 256-key region
// qm[b][n:4096]      (ushort)  query validity
// Vpart[b][c:64][chunk:16] (f32) per-256-pixel-chunk sums of V (all pixels)
#define WSQ 0
#define WSK 262144
#define WSV 524288
#define WSNV 1572864
#define WSQM 1572928
#define WSVPU 1589312          // float region at byte 3178624 (16 KB)

__device__ __forceinline__ ushort f2bf(float f) {            // RNE f32->bf16 (scalar)
    union { float f; uint u; } a; a.f = f;
    const uint u = a.u;
    return (ushort)((u + 0x7FFFu + ((u >> 16) & 1u)) >> 16);
}
// single-instruction packed f32->bf16 (RNE): dst.lo = bf16(a), dst.hi = bf16(b)
__device__ __forceinline__ uint cvtpk(float a, float b) {
    uint r;
    asm("v_cvt_pk_bf16_f32 %0, %1, %2" : "=v"(r) : "v"(a), "v"(b));
    return r;
}

// ---------------- projections -> frag-major bf16 q,k,v (region-compacted K/V) ----
// grid (64, 9): x = 256-pixel tile (== one compaction region), y = group
// (0 = q+k fused, 1..8 = v rows 8(g-1))   [proven R3 version, byte-identical]
__global__ __launch_bounds__(256) void proj_kernel(
    const float* __restrict__ x, const int* __restrict__ mask,
    const float* __restrict__ Wq, const float* __restrict__ bq,
    const float* __restrict__ Wk, const float* __restrict__ bk,
    const float* __restrict__ Wv, const float* __restrict__ bv,
    ushort* __restrict__ ws)
{
    __shared__ float wsh[16 * 64];
    __shared__ float bsh[16];
    __shared__ int   wcnt[4];
    __shared__ float wvs[4][8];
    const int g = blockIdx.y;
    const int tid = threadIdx.x;
    const int wid = tid >> 6, lane = tid & 63;
    const int nout = (g == 0) ? 16 : 8;

    if (g == 0) {
        for (int i = tid; i < 512; i += 256) { wsh[i] = Wq[i]; wsh[512 + i] = Wk[i]; }
        if (tid < 8)  bsh[tid] = bq[tid];
        else if (tid < 16) bsh[tid] = bk[tid - 8];
    } else {
        const float* W = Wv + (g - 1) * 512;
        for (int i = tid; i < 512; i += 256) wsh[i] = W[i];
        if (tid < 8) bsh[tid] = bv[(g - 1) * 8 + tid];
    }

    const int pix = blockIdx.x * 256 + tid;          // 0..16383
    const int b = pix >> 12;
    const int n = pix & (NPIX - 1);
    const int qm = mask[pix];
    const ull bal = __ballot(qm != 0);               // block-local compaction rank
    if (lane == 0) wcnt[wid] = __popcll(bal);
    __syncthreads();

    const float* xb = x + (size_t)b * CH * NPIX + n;
    float acc[16];
#pragma unroll
    for (int o = 0; o < 16; o++) acc[o] = (o < nout) ? bsh[o] : 0.f;

#pragma unroll
    for (int c4 = 0; c4 < 16; c4++) {
        float xv0 = xb[(size_t)(c4 * 4 + 0) * NPIX];
        float xv1 = xb[(size_t)(c4 * 4 + 1) * NPIX];
        float xv2 = xb[(size_t)(c4 * 4 + 2) * NPIX];
        float xv3 = xb[(size_t)(c4 * 4 + 3) * NPIX];
        if (g == 0) {
#pragma unroll
            for (int o = 0; o < 16; o++) {
                const int base = (o < 8 ? 0 : 512) + (o & 7) * 64;
                float4 w = *(const float4*)&wsh[base + c4 * 4];
                acc[o] += w.x * xv0 + w.y * xv1 + w.z * xv2 + w.w * xv3;
            }
        } else {
#pragma unroll
            for (int o = 0; o < 8; o++) {
                float4 w = *(const float4*)&wsh[o * 64 + c4 * 4];
                acc[o] += w.x * xv0 + w.y * xv1 + w.z * xv2 + w.w * xv3;
            }
        }
    }

    // compacted slot within this 256-pixel region (deterministic, no atomics)
    int offV = 0, offI = 0, nvb = 0;
#pragma unroll
    for (int w = 0; w < 4; w++) {
        const int cw = wcnt[w];
        if (w < wid) { offV += cw; offI += 64 - cw; }
        nvb += cw;
    }
    const int rankV = __popcll(bal & ((1ull << lane) - 1ull));
    const int slot = qm ? (offV + rankV) : (nvb + offI + (lane - rankV));
    const int rr = n >> 8;                       // region 0..15 (uniform per block)
    const int js = rr * 8 + (slot >> 5);         // compacted key-tile
    const int jl = slot & 31;

    if (g == 0) {
        // q: ORIGINAL position; fold log2(e); zero invalid rows; d=8 slot = qm?1:0
        {
            const int jtq = n >> 5, jlq = n & 31;
            const float s = qm ? LOG2E : 0.f;
            uint4v lo, hi;
            lo.x = cvtpk(acc[0] * s, acc[1] * s);
            lo.y = cvtpk(acc[2] * s, acc[3] * s);
            lo.z = cvtpk(acc[4] * s, acc[5] * s);
            lo.w = cvtpk(acc[6] * s, acc[7] * s);
            hi.x = qm ? 0x3F80u : 0u;   // bf16(1.0) in slot jj=0
            hi.y = 0u; hi.z = 0u; hi.w = 0u;
            ushort* qf = ws + WSQ + (size_t)b * 65536 + (size_t)jtq * 512;
            *(uint4v*)(qf + jlq * 8)       = lo;
            *(uint4v*)(qf + 256 + jlq * 8) = hi;
        }
        // k: COMPACTED position; d=8 slot = valid?0:-1e30 (tail annihilates)
        {
            uint4v lo, hi;
            lo.x = cvtpk(acc[8],  acc[9]);
            lo.y = cvtpk(acc[10], acc[11]);
            lo.z = cvtpk(acc[12], acc[13]);
            lo.w = cvtpk(acc[14], acc[15]);
            hi.x = (uint)f2bf(qm ? 0.f : -1e30f);
            hi.y = 0u; hi.z = 0u; hi.w = 0u;
            ushort* kf = ws + WSK + (size_t)b * 65536 + (size_t)js * 512;
            *(uint4v*)(kf + jl * 8)       = lo;
            *(uint4v*)(kf + 256 + jl * 8) = hi;
        }
        if (tid == 0) ws[WSNV + b * 16 + rr] = (ushort)nvb;
        ws[WSQM + pix] = (ushort)qm;
    } else {
        // v: COMPACTED frag-major vtf[b][jt][ct][h][hp][c'][jj]
        const int h = jl >> 4, hp = (jl >> 3) & 1, jj = jl & 7;
        const int c0 = (g - 1) * 8;
        ushort* vt = ws + WSV + (size_t)b * 262144;
#pragma unroll
        for (int o = 0; o < 8; o++) {
            const int c = c0 + o, ct = c >> 5, cp = c & 31;
            vt[(size_t)((((js * 2 + ct) * 2 + h) * 2 + hp) * 256) + cp * 8 + jj] = f2bf(acc[o]);
        }
        // Vpart: per-chunk f32 sums over ALL pixels (for invalid-query uniform path)
#pragma unroll
        for (int o = 0; o < 8; o++) {
            float v = acc[o];
#pragma unroll
            for (int off = 32; off; off >>= 1) v += __shfl_down(v, off);
            if (lane == 0) wvs[wid][o] = v;
        }
        __syncthreads();
        if (tid < 8) {
            const float t = wvs[0][tid] + wvs[1][tid] + wvs[2][tid] + wvs[3][tid];
            float* vpf = (float*)(ws + WSVPU);
            vpf[(b * 64 + c0 + tid) * 16 + (blockIdx.x & 15)] = t;
        }
    }
}

// ---------------- LDS-free MFMA flash attention over COMPACTED keys ----------------
// grid (64, 4): 64-query tile, 512 thr = 8 waves. Active 32-key chunks
// (lc*32 < nv[region]) are flattened into a list and round-robined over waves.
// Epilogue: TWO merge passes (one per q-tile, all 64 channels), f32x4 LDS/global.
__global__ __launch_bounds__(512, 2) void attn_kernel(
    const ushort* __restrict__ ws, const float* __restrict__ x,
    const float* __restrict__ gamma, float* __restrict__ out)
{
    __shared__ float Obuf[8][64][36];     // 73.7 KB: one q-tile (64 ch) per pass
    __shared__ float Lb[2][8][32];
    __shared__ float Linv[2][32];
    __shared__ float VmeanS[64];
    __shared__ ushort qmS[64];
    __shared__ ushort nvS[16];
    __shared__ ushort jtT[8][17];         // per-wave active-chunk list (+pad entry)

    const int tid  = threadIdx.x;
    const int wid  = tid >> 6;
    const int lane = tid & 63;
    const int hl   = lane >> 5;
    const int col  = lane & 31;
    const int b    = blockIdx.y;
    const int bx   = blockIdx.x;          // queries bx*64 .. bx*64+63

    const ushort* qf = ws + WSQ + (size_t)b * 65536 + (size_t)(2 * bx) * 512;
    const ushort* kf = ws + WSK + (size_t)b * 65536;
    const ushort* vt = ws + WSV + (size_t)b * 262144;

    const short8 qfA = *(const short8*)(qf + lane * 8);
    const short8 qfB = *(const short8*)(qf + 512 + lane * 8);

    // stage nv / qmask / Vmean
    if (tid < 16) nvS[tid] = ws[WSNV + b * 16 + tid];
    if (tid >= 64 && tid < 128) qmS[tid - 64] = ws[WSQM + b * 4096 + bx * 64 + (tid - 64)];
    if (tid >= 128 && tid < 192) {
        const int c = tid - 128;
        const float* vpf = (const float*)(ws + WSVPU);
        float s = 0.f;
#pragma unroll
        for (int k2 = 0; k2 < 16; k2++) s += vpf[(b * 64 + c) * 16 + k2];
        VmeanS[c] = s * (1.0f / 4096.0f);
    }
    __syncthreads();

    int A = 0;
#pragma unroll
    for (int r2 = 0; r2 < 16; r2++) {
        int a = ((int)nvS[r2] + 31) >> 5; if (a > 8) a = 8;
        A += a;
    }
    if (tid < 128) {                       // flatten active chunks -> (region, lc)
        const int w = tid >> 4, ii = tid & 15, ci = w + ii * 8;
        int Acc = 0, ent = 0;
#pragma unroll
        for (int r2 = 0; r2 < 16; r2++) {
            int a = ((int)nvS[r2] + 31) >> 5; if (a > 8) a = 8;
            if (ci >= Acc && ci < Acc + a) ent = r2 * 8 + (ci - Acc);
            Acc += a;
        }
        jtT[w][ii] = (ushort)ent;
    }
    if (tid < 8) jtT[tid][16] = 0;
    __syncthreads();

    const int niter = (A - wid + 7) >> 3;  // A >= 16 always

    f32x16 accA0, accA1, accB0, accB1, zf;
#pragma unroll
    for (int r = 0; r < 16; r++) { accA0[r] = 0.f; accA1[r] = 0.f; accB0[r] = 0.f; accB1[r] = 0.f; zf[r] = 0.f; }
    float lsA = 0.f, lsB = 0.f;

    // prefetch first active chunk
    int jc = jtT[wid][0];
    uint4v kn   = *(const uint4v*)(kf + (size_t)jc * 512 + lane * 8);
    uint4v vn00 = *(const uint4v*)(vt + (size_t)((jc * 2 + 0) * 2 + 0) * 512 + lane * 8);
    uint4v vn01 = *(const uint4v*)(vt + (size_t)((jc * 2 + 0) * 2 + 1) * 512 + lane * 8);
    uint4v vn10 = *(const uint4v*)(vt + (size_t)((jc * 2 + 1) * 2 + 0) * 512 + lane * 8);
    uint4v vn11 = *(const uint4v*)(vt + (size_t)((jc * 2 + 1) * 2 + 1) * 512 + lane * 8);

// exp2 -> tree lsum -> cvt_pk bf16 -> permlane32_swap B-frags -> 4 PV MFMAs
#define QK_PV(SFRAG, LSUM, A0, A1) do {                                                              \
    float p[16];                                                                                     \
    _Pragma("unroll") for (int r = 0; r < 16; r++) p[r] = __builtin_amdgcn_exp2f((SFRAG)[r]);        \
    LSUM += (((p[0] + p[1]) + (p[2] + p[3])) + ((p[4] + p[5]) + (p[6] + p[7])))                      \
          + (((p[8] + p[9]) + (p[10] + p[11])) + ((p[12] + p[13]) + (p[14] + p[15])));               \
    uint P[8];                                                                                       \
    _Pragma("unroll") for (int r = 0; r < 8; r++) P[r] = cvtpk(p[2 * r], p[2 * r + 1]);              \
    const uint2v s02 = __builtin_amdgcn_permlane32_swap(P[0], P[2], false, false);                   \
    const uint2v s13 = __builtin_amdgcn_permlane32_swap(P[1], P[3], false, false);                   \
    const uint2v s46 = __builtin_amdgcn_permlane32_swap(P[4], P[6], false, false);                   \
    const uint2v s57 = __builtin_amdgcn_permlane32_swap(P[5], P[7], false, false);                   \
    uint4v B0, B1;                                                                                   \
    B0.x = s02.x; B0.y = s13.x; B0.z = s02.y; B0.w = s13.y;                                          \
    B1.x = s46.x; B1.y = s57.x; B1.z = s46.y; B1.w = s57.y;                                          \
    __builtin_amdgcn_s_setprio(1);                                                                   \
    A0 = __builtin_amdgcn_mfma_f32_32x32x16_bf16(*(const short8*)&c00, *(const short8*)&B0, A0, 0, 0, 0); \
    A0 = __builtin_amdgcn_mfma_f32_32x32x16_bf16(*(const short8*)&c01, *(const short8*)&B1, A0, 0, 0, 0); \
    A1 = __builtin_amdgcn_mfma_f32_32x32x16_bf16(*(const short8*)&c10, *(const short8*)&B0, A1, 0, 0, 0); \
    A1 = __builtin_amdgcn_mfma_f32_32x32x16_bf16(*(const short8*)&c11, *(const short8*)&B1, A1, 0, 0, 0); \
    __builtin_amdgcn_s_setprio(0);                                                                   \
} while (0)

    for (int i = 0; i < niter; i++) {
        const int jn = jtT[wid][i + 1];
        const uint4v kc = kn, c00 = vn00, c01 = vn01, c10 = vn10, c11 = vn11;
        if (i + 1 < niter) {                 // prefetch next active chunk
            kn   = *(const uint4v*)(kf + (size_t)jn * 512 + lane * 8);
            vn00 = *(const uint4v*)(vt + (size_t)((jn * 2 + 0) * 2 + 0) * 512 + lane * 8);
            vn01 = *(const uint4v*)(vt + (size_t)((jn * 2 + 0) * 2 + 1) * 512 + lane * 8);
            vn10 = *(const uint4v*)(vt + (size_t)((jn * 2 + 1) * 2 + 0) * 512 + lane * 8);
            vn11 = *(const uint4v*)(vt + (size_t)((jn * 2 + 1) * 2 + 1) * 512 + lane * 8);
        }

        const f32x16 sA = __builtin_amdgcn_mfma_f32_32x32x16_bf16(*(const short8*)&kc, qfA, zf, 0, 0, 0);
        const f32x16 sB = __builtin_amdgcn_mfma_f32_32x32x16_bf16(*(const short8*)&kc, qfB, zf, 0, 0, 0);

        QK_PV(sA, lsA, accA0, accA1);
        QK_PV(sB, lsB, accB0, accB1);
    }
#undef QK_PV

    // ---- 8-way wave merge (waves held disjoint key chunks) ----
    const float lwA = lsA + __shfl_xor(lsA, 32);
    const float lwB = lsB + __shfl_xor(lsB, 32);
    if (hl == 0) { Lb[0][wid][col] = lwA; Lb[1][wid][col] = lwB; }
    __syncthreads();
    if (tid < 64) {
        const int q = tid >> 5, m = tid & 31;
        float s = 0.f;
#pragma unroll
        for (int w = 0; w < 8; w++) s += Lb[q][w][m];
        Linv[q][m] = 1.f / s;
    }

    const float gm = gamma[0];

// one q-tile merge pass: stage all 64 channels of 8 waves' partial O^T,
// 8-way f32x4 reduce, fused f32x4 epilogue with invalid-query override
#define MERGE_PASS(A0v, A1v, QSEL) do {                                                              \
    __syncthreads();                                                                                 \
    _Pragma("unroll") for (int r = 0; r < 16; r++) {                                                 \
        const int crow = (r & 3) + 8 * (r >> 2) + 4 * hl;    /* verified 32x32 C/D mapping */        \
        Obuf[wid][crow][col]      = (A0v)[r];                                                        \
        Obuf[wid][32 + crow][col] = (A1v)[r];                                                        \
    }                                                                                                \
    __syncthreads();                                                                                 \
    {                                                                                                \
        const int c = tid >> 3, m0 = (tid & 7) * 4;                                                  \
        f32x4 o = {0.f, 0.f, 0.f, 0.f};                                                              \
        _Pragma("unroll") for (int w = 0; w < 8; w++) o += *(const f32x4*)&Obuf[w][c][m0];            \
        const int mi = (QSEL) * 32 + m0;                                                             \
        const size_t base = (((size_t)(b * CH + c)) << 12) + bx * 64 + (QSEL) * 32 + m0;             \
        const f32x4 xv = *(const f32x4*)&x[base];                                                    \
        f32x4 rv;                                                                                    \
        _Pragma("unroll") for (int u = 0; u < 4; u++)                                                \
            rv[u] = (qmS[mi + u] ? gm * o[u] * Linv[QSEL][m0 + u] : gm * VmeanS[c]) + xv[u];         \
        *(f32x4*)&out[base] = rv;                                                                    \
    }                                                                                                \
} while (0)

    MERGE_PASS(accA0, accA1, 0);
    MERGE_PASS(accB0, accB1, 1);
#undef MERGE_PASS
}

extern "C" void kernel_launch(void* const* d_in, const int* in_sizes, int n_in,
                              void* d_out, int out_size, void* d_ws, size_t ws_size,
                              hipStream_t stream) {
    const float* x     = (const float*)d_in[0];
    const int*   mask  = (const int*)d_in[1];
    const float* Wq    = (const float*)d_in[2];
    const float* bq    = (const float*)d_in[3];
    const float* Wk    = (const float*)d_in[4];
    const float* bk    = (const float*)d_in[5];
    const float* Wv    = (const float*)d_in[6];
    const float* bv    = (const float*)d_in[7];
    const float* gamma = (const float*)d_in[8];
    float* out  = (float*)d_out;
    ushort* ws  = (ushort*)d_ws;     // ~3.2 MB used

    proj_kernel<<<dim3(64, 9), 256, 0, stream>>>(x, mask, Wq, bq, Wk, bk, Wv, bv, ws);
    attn_kernel<<<dim3(64, 4), 512, 0, stream>>>(ws, x, gamma, out);
}